// Round 10
// baseline (39.469 us; speedup 1.0000x reference)
//
#include <hip/hip_runtime.h>
#include <math.h>

#define SRATE   24000.0
#define NB      8
#define NT      48000
#define NH      60
#define NC      100
#define NFMT    5
#define CTS     64
#define NCH     (NT / CTS)       // 750 chunks per batch
#define NPAIR   (NCH / 2)        // 375 chunk-pairs (128 ts per wave)
#define TWO_PI  6.283185307179586476925286766559
#define PSC     (1.0f / 1024.0f) // exact 2^-10 prescale
#define NYQS    11.71875f        // 12000 * 2^-10

typedef float v2f __attribute__((ext_vector_type(2)));

// ---------------- kernel 1: per-chunk f0 sums (double) ----------------
__global__ __launch_bounds__(256) void k_partial(const float* __restrict__ f0,
                                                 double* __restrict__ part) {
    int b = blockIdx.y;
    int ch = blockIdx.x * 4 + (threadIdx.x >> 6);
    int lane = threadIdx.x & 63;
    if (ch < NCH) {
        int t = ch * CTS + lane;
        double q = (double)f0[b * NT + t];
        #pragma unroll
        for (int off = 32; off > 0; off >>= 1)
            q += __shfl_down(q, off, 64);
        if (lane == 0) part[b * NCH + ch] = q;
    }
}

// ---------------- kernel 2: main synthesis ----------------
// 256 threads = 4 waves; each wave owns 128 ts (8 passes of 16 ts x 4 lanes).
// Load-issue order exploits in-order vmcnt retirement: preamble loads
// (f0, tables, part) FIRST, then 3 pass-sets of amp loads. Preamble compute
// waits only on the early loads while amps stay in flight; rolling 3-deep
// register prefetch keeps >=2 passes (~1600 cyc) of cover per amp set.
__global__ __launch_bounds__(256, 3) void k_main(const float* __restrict__ f0,
                                                 const float* __restrict__ amps,
                                                 const float* __restrict__ ffq,
                                                 const float* __restrict__ fbw,
                                                 const float* __restrict__ fam,
                                                 const float* __restrict__ initp,
                                                 const double* __restrict__ part,
                                                 float* __restrict__ out) {
    int b = blockIdx.y;
    int cp = blockIdx.x * 4 + (threadIdx.x >> 6);
    int lane = threadIdx.x & 63;
    if (cp >= NPAIR) return;
    int ch0 = cp * 2;
    int t0 = cp * 128;
    int g0 = lane >> 2, j = lane & 3;
    const float4 f4z = make_float4(0.f, 0.f, 0.f, 0.f);
    const float* ab = amps + (size_t)b * NT * NH;

    // ===== load-issue phase 1: everything the preamble needs =====
    float f0A = f0[b * NT + t0 + lane];
    float f0B = f0[b * NT + t0 + 64 + lane];

    double srcA = (double)(t0 + lane) * (99.0 / 47999.0);
    int iA = (int)srcA; if (iA > NC - 2) iA = NC - 2;
    float frA = (float)(srcA - (double)iA), omA = 1.0f - frA;
    double srcB = (double)(t0 + 64 + lane) * (99.0 / 47999.0);
    int iB = (int)srcB; if (iB > NC - 2) iB = NC - 2;
    float frB = (float)(srcB - (double)iB), omB = 1.0f - frB;

    const float* FqA = ffq + (b * NC + iA) * NFMT;
    const float* BwA = fbw + (b * NC + iA) * NFMT;
    const float* AmA = fam + (b * NC + iA) * NFMT;
    const float* FqB = ffq + (b * NC + iB) * NFMT;
    const float* BwB = fbw + (b * NC + iB) * NFMT;
    const float* AmB = fam + (b * NC + iB) * NFMT;
    float tA[30], tB[30];
    #pragma unroll
    for (int f = 0; f < NFMT; ++f) {
        tA[f]      = FqA[f]; tA[5 + f]  = FqA[NFMT + f];
        tA[10 + f] = BwA[f]; tA[15 + f] = BwA[NFMT + f];
        tA[20 + f] = AmA[f]; tA[25 + f] = AmA[NFMT + f];
        tB[f]      = FqB[f]; tB[5 + f]  = FqB[NFMT + f];
        tB[10 + f] = BwB[f]; tB[15 + f] = BwB[NFMT + f];
        tB[20 + f] = AmB[f]; tB[25 + f] = AmB[NFMT + f];
    }
    const double* pb = part + b * NCH;
    double pv[12];
    #pragma unroll
    for (int k = 0; k < 12; ++k) {
        int idx = k * 64 + lane;
        pv[k] = (idx < NCH) ? pb[idx] : 0.0;
    }

    // ===== load-issue phase 2: amp sets for passes 0,1,2 =====
    #define AMPLD(S0, S1, S2, S3, p)                                          \
        { const float4* rr =                                                  \
              (const float4*)(ab + (size_t)(t0 + (p) * 16 + g0) * NH);        \
          S0 = rr[j * 4]; S1 = rr[j * 4 + 1]; S2 = rr[j * 4 + 2];             \
          S3 = (j < 3) ? rr[j * 4 + 3] : f4z; }
    float4 P0, P1, P2, P3, Q0, Q1, Q2, Q3, R0, R1, R2, R3;
    AMPLD(P0, P1, P2, P3, 0)
    AMPLD(Q0, Q1, Q2, Q3, 1)
    AMPLD(R0, R1, R2, R3, 2)

    // ===== preamble compute (amps still in flight) =====
    double sl = 0.0, sa = 0.0;
    #pragma unroll
    for (int k = 0; k < 12; ++k) {
        int idx = k * 64 + lane;
        sa += pv[k];
        if (idx < ch0) sl += pv[k];
    }
    #pragma unroll
    for (int off = 1; off < 64; off <<= 1) {
        sl += __shfl_xor(sl, off, 64);
        sa += __shfl_xor(sa, off, 64);
    }
    double initrev = (double)initp[b] * (1.0 / TWO_PI);
    if (cp == 0 && lane == 0) {
        double rv = sa * (1.0 / SRATE) + initrev;
        out[NB * NT + b] = (float)((rv - floor(rv)) * TWO_PI);
    }

    // f64 scans (lane = ts within chunk)
    double incA = (double)f0A, incB = (double)f0B;
    #pragma unroll
    for (int off = 1; off < 64; off <<= 1) {
        double nA = __shfl_up(incA, off, 64);
        double nB = __shfl_up(incB, off, 64);
        if (lane >= off) { incA += nA; incB += nB; }
    }
    double totA = __shfl(incA, 63, 64);
    double rA = (sl + incA) * (1.0 / SRATE) + initrev;
    double rB = (sl + totA + incB) * (1.0 / SRATE) + initrev;
    float revA = (float)(rA - floor(rA));
    float revB = (float)(rB - floor(rB));
    float f0sA = f0A * PSC;
    float f0sB = f0B * PSC;

    // lerp coefficients (per-lane, shuffled to groups inside passes)
    float fqA[NFMT], c1A[NFMT], c2A[NFMT], fqB[NFMT], c1B[NFMT], c2B[NFMT];
    #pragma unroll
    for (int f = 0; f < NFMT; ++f) {
        float fq = tA[f] * omA + tA[5 + f] * frA;
        float bw = tA[10 + f] * omA + tA[15 + f] * frA;
        float am = tA[20 + f] * omA + tA[25 + f] * frA;
        float bws = bw * PSC;
        fqA[f] = fq * PSC; c2A[f] = bws * bws; c1A[f] = am * c2A[f];
        fq = tB[f] * omB + tB[5 + f] * frB;
        bw = tB[10 + f] * omB + tB[15 + f] * frB;
        am = tB[20 + f] * omB + tB[25 + f] * frB;
        bws = bw * PSC;
        fqB[f] = fq * PSC; c2B[f] = bws * bws; c1B[f] = am * c2B[f];
    }

    // ===== one pass = 16 ts x 4 lanes, 16 contiguous harmonics per lane =====
    auto do_pass = [&](int p, float revLane, float f0sLane,
                       const float (&fqL)[NFMT], const float (&c1L)[NFMT],
                       const float (&c2L)[NFMT],
                       float4 q0, float4 q1, float4 q2, float4 q3) {
        int gp = ((p & 3) << 4) + g0;
        float f0s   = __shfl(f0sLane, gp, 64);
        float rev_g = __shfl(revLane, gp, 64);
        float fq[NFMT], c1[NFMT], c2[NFMT];
        #pragma unroll
        for (int f = 0; f < NFMT; ++f) {
            fq[f] = __shfl(fqL[f], gp, 64);
            c1[f] = __shfl(c1L[f], gp, 64);
            c2[f] = __shfl(c2L[f], gp, 64);
        }
        float hb = (float)(j << 4);
        auto sd = [&](float k) {
            return __builtin_amdgcn_sinf(
                __builtin_amdgcn_fractf((hb + k) * rev_g));
        };
        float cc = __builtin_amdgcn_cosf(
            __builtin_amdgcn_fractf(2.0f * rev_g));     // cos(2*theta)
        v2f cv = {2.0f * cc, 2.0f * cc};
        v2f pr0 = {sd(1.0f), sd(2.0f)};
        v2f pr1 = {sd(3.0f), sd(4.0f)};
        v2f pr2 = cv * pr1 - pr0;
        v2f pr3 = cv * pr2 - pr1;
        v2f pr4 = {sd(9.0f), sd(10.0f)};
        v2f pr5 = {sd(11.0f), sd(12.0f)};
        v2f pr6 = cv * pr5 - pr4;
        v2f pr7 = cv * pr6 - pr5;
        v2f acc2 = {0.0f, 0.0f};
        auto pairf = [&](float h1, v2f sn, float a0, float a1) {
            v2f hfl = {h1, h1 + 1.0f};
            v2f hs = f0s * hfl;
            v2f pN = {1.0f, 1.0f}, pD = {1.0f, 1.0f};
            #pragma unroll
            for (int f = 0; f < NFMT; ++f) {
                v2f d = hs - fq[f];
                v2f e = d * d + c2[f];
                pN *= e + c1[f];
                pD *= e;
            }
            float R = __builtin_amdgcn_rcpf(pD.x * pD.y);
            v2f fac = {pN.x * pD.y * R, pN.y * pD.x * R};
            v2f fm;
            fm.x = (hs.x < NYQS) ? fac.x : 0.0f;
            fm.y = (hs.y < NYQS) ? fac.y : 0.0f;
            v2f aa = {a0, a1};
            acc2 += (sn * aa) * fm;
        };
        pairf(hb + 1.0f,  pr0, q0.x, q0.y);
        pairf(hb + 3.0f,  pr1, q0.z, q0.w);
        pairf(hb + 5.0f,  pr2, q1.x, q1.y);
        pairf(hb + 7.0f,  pr3, q1.z, q1.w);
        pairf(hb + 9.0f,  pr4, q2.x, q2.y);
        pairf(hb + 11.0f, pr5, q2.z, q2.w);
        pairf(hb + 13.0f, pr6, q3.x, q3.y);
        pairf(hb + 15.0f, pr7, q3.z, q3.w);
        float acc = acc2.x + acc2.y;
        acc += __shfl_xor(acc, 1, 64);
        acc += __shfl_xor(acc, 2, 64);
        if (j == 0) {
            if (!(f0s > 0.0f)) acc = 0.0f;              // voiced mask
            out[b * NT + t0 + (p << 4) + g0] = acc;
        }
    };

    // ===== 8 passes, rolling 3-deep static prefetch =====
    do_pass(0, revA, f0sA, fqA, c1A, c2A, P0, P1, P2, P3);
    AMPLD(P0, P1, P2, P3, 3)
    do_pass(1, revA, f0sA, fqA, c1A, c2A, Q0, Q1, Q2, Q3);
    AMPLD(Q0, Q1, Q2, Q3, 4)
    do_pass(2, revA, f0sA, fqA, c1A, c2A, R0, R1, R2, R3);
    AMPLD(R0, R1, R2, R3, 5)
    do_pass(3, revA, f0sA, fqA, c1A, c2A, P0, P1, P2, P3);
    AMPLD(P0, P1, P2, P3, 6)
    do_pass(4, revB, f0sB, fqB, c1B, c2B, Q0, Q1, Q2, Q3);
    AMPLD(Q0, Q1, Q2, Q3, 7)
    do_pass(5, revB, f0sB, fqB, c1B, c2B, R0, R1, R2, R3);
    do_pass(6, revB, f0sB, fqB, c1B, c2B, P0, P1, P2, P3);
    do_pass(7, revB, f0sB, fqB, c1B, c2B, Q0, Q1, Q2, Q3);
    #undef AMPLD
}

extern "C" void kernel_launch(void* const* d_in, const int* in_sizes, int n_in,
                              void* d_out, int out_size, void* d_ws, size_t ws_size,
                              hipStream_t stream) {
    const float* f0    = (const float*)d_in[0];
    const float* amps  = (const float*)d_in[1];
    const float* ffq   = (const float*)d_in[2];
    const float* fbw   = (const float*)d_in[3];
    const float* fam   = (const float*)d_in[4];
    const float* initp = (const float*)d_in[5];
    float* out = (float*)d_out;

    double* part = (double*)d_ws;                    // NB*NCH doubles (48 KB)

    dim3 gpart((NCH + 3) / 4, NB);
    k_partial<<<gpart, 256, 0, stream>>>(f0, part);
    dim3 gmain((NPAIR + 3) / 4, NB);
    k_main<<<gmain, 256, 0, stream>>>(f0, amps, ffq, fbw, fam, initp, part, out);
}

// Round 11
// 33.450 us; speedup vs baseline: 1.1800x; 1.1800x over previous
//
#include <hip/hip_runtime.h>
#include <math.h>

#define SRATE   24000.0
#define NB      8
#define NT      48000
#define NH      60
#define NC      100
#define NFMT    5
#define CTS     64
#define NCH     (NT / CTS)       // 750 chunks per batch
#define NPAIR   (NCH / 2)        // 375 chunk-pairs (128 ts per wave)
#define TWO_PI  6.283185307179586476925286766559
#define PSC     (1.0f / 1024.0f) // exact 2^-10 prescale
#define NYQS    11.71875f        // 12000 * 2^-10

typedef float v2f __attribute__((ext_vector_type(2)));

// ---------------- kernel 1: per-chunk f0 sums (double) ----------------
__global__ __launch_bounds__(256) void k_partial(const float* __restrict__ f0,
                                                 double* __restrict__ part) {
    int b = blockIdx.y;
    int ch = blockIdx.x * 4 + (threadIdx.x >> 6);
    int lane = threadIdx.x & 63;
    if (ch < NCH) {
        int t = ch * CTS + lane;
        double q = (double)f0[b * NT + t];
        #pragma unroll
        for (int off = 32; off > 0; off >>= 1)
            q += __shfl_down(q, off, 64);
        if (lane == 0) part[b * NCH + ch] = q;
    }
}

// ---------------- kernel 2: main synthesis ----------------
// 256 threads = 4 waves; each wave owns 128 ts (8 passes of 16 ts x 4 lanes).
// Amp loads use group-contiguous indexing rr[i*4+j]: within one VMEM
// instruction each 4-lane group reads one consecutive 64B region (~16-28
// cache lines/inst instead of ~60) -> 2-3x fewer L1 transactions.
// Lane j owns harmonic quads {4j+1..4j+4} + {0,16,32,48}; sines: quads 0,1
// seeded (8 v_sin), quads 2,3 via s(h+16) = 2cos(16th)s(h) - s(h-16).
__global__ __launch_bounds__(256) void k_main(const float* __restrict__ f0,
                                              const float* __restrict__ amps,
                                              const float* __restrict__ ffq,
                                              const float* __restrict__ fbw,
                                              const float* __restrict__ fam,
                                              const float* __restrict__ initp,
                                              const double* __restrict__ part,
                                              float* __restrict__ out) {
    int b = blockIdx.y;
    int cp = blockIdx.x * 4 + (threadIdx.x >> 6);
    int lane = threadIdx.x & 63;
    if (cp >= NPAIR) return;
    int ch0 = cp * 2;
    int t0 = cp * 128;                 // first ts of this wave (within batch)
    int g0 = lane >> 2, j = lane & 3;
    const float4 f4z = make_float4(0.f, 0.f, 0.f, 0.f);

    const float* ab = amps + (size_t)b * NT * NH;

    // group-contiguous amp loads: instruction i reads float4 #(i*4+j)
    #define AMPLD(S0, S1, S2, S3, p)                                          \
        { const float4* rr =                                                  \
              (const float4*)(ab + (size_t)(t0 + (p) * 16 + g0) * NH);        \
          S0 = rr[j]; S1 = rr[4 + j]; S2 = rr[8 + j];                         \
          S3 = (j < 3) ? rr[12 + j] : f4z; }

    // ---- prologue amp loads: passes 0 and 1, issued at cycle 0 ----
    float4 A0, A1, A2, A3, B0, B1, B2, B3;
    AMPLD(A0, A1, A2, A3, 0)
    AMPLD(B0, B1, B2, B3, 1)

    // ---- per-wave prefix over chunk sums (masked reduce, L2-broadcast) ----
    const double* pb = part + b * NCH;
    double sl = 0.0;
    #pragma unroll
    for (int k = 0; k < 12; ++k) {
        int idx = k * 64 + lane;
        double v = (idx < NCH) ? pb[idx] : 0.0;
        if (idx < ch0) sl += v;
    }
    #pragma unroll
    for (int off = 1; off < 64; off <<= 1)
        sl += __shfl_xor(sl, off, 64);

    double initrev = (double)initp[b] * (1.0 / TWO_PI);

    // designated wave writes final phase
    if (cp == 0) {
        double sa = 0.0;
        #pragma unroll
        for (int k = 0; k < 12; ++k) {
            int idx = k * 64 + lane;
            if (idx < NCH) sa += pb[idx];
        }
        #pragma unroll
        for (int off = 1; off < 64; off <<= 1)
            sa += __shfl_xor(sa, off, 64);
        if (lane == 0) {
            double rv = sa * (1.0 / SRATE) + initrev;
            out[NB * NT + b] = (float)((rv - floor(rv)) * TWO_PI);
        }
    }

    // ---- per-chunk preamble: f64 scan + formant lerp (lane = ts) ----
    float revA, f0sA, revB, f0sB;
    float fqA[NFMT], c1A[NFMT], c2A[NFMT], fqB[NFMT], c1B[NFMT], c2B[NFMT];

    auto chunk_pre = [&](int tl, double prefd, float& rev_o, float& f0s_o,
                         float (&fqo)[NFMT], float (&c1o)[NFMT],
                         float (&c2o)[NFMT]) -> double {
        float f0v = f0[b * NT + tl];
        double inc = (double)f0v;
        #pragma unroll
        for (int off = 1; off < 64; off <<= 1) {
            double n = __shfl_up(inc, off, 64);
            if (lane >= off) inc += n;
        }
        double rev = (prefd + inc) * (1.0 / SRATE) + initrev;
        rev_o = (float)(rev - floor(rev));
        f0s_o = f0v * PSC;
        double srcd = (double)tl * (99.0 / 47999.0);
        int i0 = (int)srcd;
        if (i0 > NC - 2) i0 = NC - 2;
        float frac = (float)(srcd - (double)i0);
        float omf = 1.0f - frac;
        const float* Fq = ffq + (b * NC + i0) * NFMT;
        const float* Bw = fbw + (b * NC + i0) * NFMT;
        const float* Am = fam + (b * NC + i0) * NFMT;
        #pragma unroll
        for (int f = 0; f < NFMT; ++f) {
            float fqv = Fq[f] * omf + Fq[NFMT + f] * frac;
            float bwv = Bw[f] * omf + Bw[NFMT + f] * frac;
            float amv = Am[f] * omf + Am[NFMT + f] * frac;
            float bws = bwv * PSC;
            fqo[f] = fqv * PSC;
            c2o[f] = bws * bws;
            c1o[f] = amv * c2o[f];
        }
        return __shfl(inc, 63, 64);        // chunk total (all lanes)
    };

    double tot0 = chunk_pre(t0 + lane, sl, revA, f0sA, fqA, c1A, c2A);
    chunk_pre(t0 + 64 + lane, sl + tot0, revB, f0sB, fqB, c1B, c2B);

    // ---- one pass = 16 ts x 4 lanes; lane j: quads {4j+1..4} +0/16/32/48 ----
    auto do_pass = [&](int p, float revLane, float f0sLane,
                       const float (&fqL)[NFMT], const float (&c1L)[NFMT],
                       const float (&c2L)[NFMT],
                       float4 q0, float4 q1, float4 q2, float4 q3) {
        int gp = ((p & 3) << 4) + g0;
        float f0s   = __shfl(f0sLane, gp, 64);
        float rev_g = __shfl(revLane, gp, 64);
        float fq[NFMT], c1[NFMT], c2[NFMT];
        #pragma unroll
        for (int f = 0; f < NFMT; ++f) {
            fq[f] = __shfl(fqL[f], gp, 64);
            c1[f] = __shfl(c1L[f], gp, 64);
            c2[f] = __shfl(c2L[f], gp, 64);
        }
        float hb = (float)(j << 2);
        auto sd = [&](float k) {
            return __builtin_amdgcn_sinf(
                __builtin_amdgcn_fractf((hb + k) * rev_g));
        };
        // seeds: quad0 (hb+1..4), quad1 (hb+17..20)
        v2f s01 = {sd(1.0f),  sd(2.0f)};
        v2f s23 = {sd(3.0f),  sd(4.0f)};
        v2f s45 = {sd(17.0f), sd(18.0f)};
        v2f s67 = {sd(19.0f), sd(20.0f)};
        float c16 = __builtin_amdgcn_cosf(
            __builtin_amdgcn_fractf(16.0f * rev_g));    // cos(16*theta)
        v2f cv = {2.0f * c16, 2.0f * c16};
        v2f s89 = cv * s45 - s01;                       // quad2 a (hb+33,34)
        v2f sAB = cv * s67 - s23;                       // quad2 b (hb+35,36)
        v2f sCD = cv * s89 - s45;                       // quad3 a (hb+49,50)
        v2f sEF = cv * sAB - s67;                       // quad3 b (hb+51,52)
        v2f acc2 = {0.0f, 0.0f};
        auto pairf = [&](float h1, v2f sn, float a0, float a1) {
            v2f hfl = {h1, h1 + 1.0f};
            v2f hs = f0s * hfl;                         // f0*h * 2^-10
            v2f pN = {1.0f, 1.0f}, pD = {1.0f, 1.0f};
            #pragma unroll
            for (int f = 0; f < NFMT; ++f) {
                v2f d = hs - fq[f];
                v2f e = d * d + c2[f];
                pN *= e + c1[f];
                pD *= e;
            }
            float R = __builtin_amdgcn_rcpf(pD.x * pD.y);
            v2f fac = {pN.x * pD.y * R, pN.y * pD.x * R};
            v2f fm;
            fm.x = (hs.x < NYQS) ? fac.x : 0.0f;        // nyquist mask
            fm.y = (hs.y < NYQS) ? fac.y : 0.0f;
            v2f aa = {a0, a1};
            acc2 += (sn * aa) * fm;
        };
        pairf(hb + 1.0f,  s01, q0.x, q0.y);
        pairf(hb + 3.0f,  s23, q0.z, q0.w);
        pairf(hb + 17.0f, s45, q1.x, q1.y);
        pairf(hb + 19.0f, s67, q1.z, q1.w);
        pairf(hb + 33.0f, s89, q2.x, q2.y);
        pairf(hb + 35.0f, sAB, q2.z, q2.w);
        pairf(hb + 49.0f, sCD, q3.x, q3.y);
        pairf(hb + 51.0f, sEF, q3.z, q3.w);
        float acc = acc2.x + acc2.y;
        acc += __shfl_xor(acc, 1, 64);
        acc += __shfl_xor(acc, 2, 64);
        if (j == 0) {
            if (!(f0s > 0.0f)) acc = 0.0f;              // voiced mask
            out[b * NT + t0 + (p << 4) + g0] = acc;
        }
    };

    // ---- 8 passes, register double-buffered, runtime loop (I-cache) ----
    #pragma unroll 1
    for (int pg = 0; pg < 8; pg += 2) {
        bool cB = pg >= 4;
        float revL = cB ? revB : revA;
        float f0sL = cB ? f0sB : f0sA;
        float fqL[NFMT], c1L[NFMT], c2L[NFMT];
        #pragma unroll
        for (int f = 0; f < NFMT; ++f) {
            fqL[f] = cB ? fqB[f] : fqA[f];
            c1L[f] = cB ? c1B[f] : c1A[f];
            c2L[f] = cB ? c2B[f] : c2A[f];
        }
        do_pass(pg, revL, f0sL, fqL, c1L, c2L, A0, A1, A2, A3);
        if (pg < 6) {
            AMPLD(A0, A1, A2, A3, pg + 2)
        }
        do_pass(pg + 1, revL, f0sL, fqL, c1L, c2L, B0, B1, B2, B3);
        if (pg < 6) {
            AMPLD(B0, B1, B2, B3, pg + 3)
        }
    }
    #undef AMPLD
}

extern "C" void kernel_launch(void* const* d_in, const int* in_sizes, int n_in,
                              void* d_out, int out_size, void* d_ws, size_t ws_size,
                              hipStream_t stream) {
    const float* f0    = (const float*)d_in[0];
    const float* amps  = (const float*)d_in[1];
    const float* ffq   = (const float*)d_in[2];
    const float* fbw   = (const float*)d_in[3];
    const float* fam   = (const float*)d_in[4];
    const float* initp = (const float*)d_in[5];
    float* out = (float*)d_out;

    double* part = (double*)d_ws;                    // NB*NCH doubles (48 KB)

    dim3 gpart((NCH + 3) / 4, NB);
    k_partial<<<gpart, 256, 0, stream>>>(f0, part);
    dim3 gmain((NPAIR + 3) / 4, NB);
    k_main<<<gmain, 256, 0, stream>>>(f0, amps, ffq, fbw, fam, initp, part, out);
}

// Round 12
// 33.059 us; speedup vs baseline: 1.1939x; 1.0118x over previous
//
#include <hip/hip_runtime.h>
#include <math.h>

#define SRATE   24000.0
#define NB      8
#define NT      48000
#define NH      60
#define NC      100
#define NFMT    5
#define CTS     64
#define NCH     (NT / CTS)       // 750 chunks per batch (= waves per batch)
#define TWO_PI  6.283185307179586476925286766559
#define PSC     (1.0f / 1024.0f) // exact 2^-10 prescale
#define NYQS    11.71875f        // 12000 * 2^-10

typedef float v2f __attribute__((ext_vector_type(2)));

// ---------------- kernel 1: per-chunk f0 sums (double) ----------------
__global__ __launch_bounds__(256) void k_partial(const float* __restrict__ f0,
                                                 double* __restrict__ part) {
    int b = blockIdx.y;
    int ch = blockIdx.x * 4 + (threadIdx.x >> 6);
    int lane = threadIdx.x & 63;
    if (ch < NCH) {
        int t = ch * CTS + lane;
        double q = (double)f0[b * NT + t];
        #pragma unroll
        for (int off = 32; off > 0; off >>= 1)
            q += __shfl_down(q, off, 64);
        if (lane == 0) part[b * NCH + ch] = q;
    }
}

// ---------------- kernel 2: main synthesis ----------------
// 256 threads = 4 waves; each wave owns ONE 64-ts chunk (4 passes of 16 ts
// x 4 lanes). Slimmed live state (one coeff bank, f32 in-chunk scan) to fit
// <=128 VGPR -> 16 waves/CU (4/SIMD) for latency hiding. Chunk-prefix from
// part[] (L2 reduce); amp loads group-contiguous, double-buffered.
__global__ __launch_bounds__(256, 4) void k_main(const float* __restrict__ f0,
                                                 const float* __restrict__ amps,
                                                 const float* __restrict__ ffq,
                                                 const float* __restrict__ fbw,
                                                 const float* __restrict__ fam,
                                                 const float* __restrict__ initp,
                                                 const double* __restrict__ part,
                                                 float* __restrict__ out) {
    int b = blockIdx.y;
    int ch = blockIdx.x * 4 + (threadIdx.x >> 6);
    int lane = threadIdx.x & 63;
    if (ch >= NCH) return;
    int t0 = ch * CTS;
    int g0 = lane >> 2, j = lane & 3;
    const float4 f4z = make_float4(0.f, 0.f, 0.f, 0.f);
    const float* ab = amps + (size_t)b * NT * NH;

    // group-contiguous amp loads: instruction i reads float4 #(i*4+j)
    #define AMPLD(S0, S1, S2, S3, p)                                          \
        { const float4* rr =                                                  \
              (const float4*)(ab + (size_t)(t0 + (p) * 16 + g0) * NH);        \
          S0 = rr[j]; S1 = rr[4 + j]; S2 = rr[8 + j];                         \
          S3 = (j < 3) ? rr[12 + j] : f4z; }

    // ---- amp loads for passes 0,1 issue at cycle 0 ----
    float4 A0, A1, A2, A3, B0, B1, B2, B3;
    AMPLD(A0, A1, A2, A3, 0)
    AMPLD(B0, B1, B2, B3, 1)

    // ---- preamble (covers amp latency): prefix, lerp, scan ----
    const double* pb = part + b * NCH;
    double sl = 0.0;
    #pragma unroll
    for (int k = 0; k < 12; ++k) {
        int idx = k * 64 + lane;
        double v = (idx < NCH) ? pb[idx] : 0.0;
        if (idx < ch) sl += v;
    }
    #pragma unroll
    for (int off = 1; off < 64; off <<= 1)
        sl += __shfl_xor(sl, off, 64);

    double initrev = (double)initp[b] * (1.0 / TWO_PI);

    if (ch == 0) {                       // designated wave: final phase
        double sa = 0.0;
        #pragma unroll
        for (int k = 0; k < 12; ++k) {
            int idx = k * 64 + lane;
            if (idx < NCH) sa += pb[idx];
        }
        #pragma unroll
        for (int off = 1; off < 64; off <<= 1)
            sa += __shfl_xor(sa, off, 64);
        if (lane == 0) {
            double rv = sa * (1.0 / SRATE) + initrev;
            out[NB * NT + b] = (float)((rv - floor(rv)) * TWO_PI);
        }
    }

    // chunk-uniform fractional prefix (f64 once), then f32 in-chunk scan
    double pfrac = sl * (1.0 / SRATE) + initrev;
    float prefF = (float)(pfrac - floor(pfrac));     // [0,1), wave-uniform

    float f0v = f0[b * NT + t0 + lane];
    float incf = f0v;
    #pragma unroll
    for (int off = 1; off < 64; off <<= 1) {
        float n = __shfl_up(incf, off, 64);
        if (lane >= off) incf += n;
    }
    float rev_l = __builtin_amdgcn_fractf(prefF + incf * (1.0f / 24000.0f));
    float f0s_l = f0v * PSC;

    // formant lerp (lane = ts), 15 coeffs
    double srcd = (double)(t0 + lane) * (99.0 / 47999.0);
    int i0 = (int)srcd;
    if (i0 > NC - 2) i0 = NC - 2;
    float frac = (float)(srcd - (double)i0);
    float omf = 1.0f - frac;
    const float* Fq = ffq + (b * NC + i0) * NFMT;
    const float* Bw = fbw + (b * NC + i0) * NFMT;
    const float* Am = fam + (b * NC + i0) * NFMT;
    float fqs[NFMT], c1s[NFMT], c2s[NFMT];
    #pragma unroll
    for (int f = 0; f < NFMT; ++f) {
        float fqv = Fq[f] * omf + Fq[NFMT + f] * frac;
        float bwv = Bw[f] * omf + Bw[NFMT + f] * frac;
        float amv = Am[f] * omf + Am[NFMT + f] * frac;
        float bws = bwv * PSC;
        fqs[f] = fqv * PSC;
        c2s[f] = bws * bws;
        c1s[f] = amv * c2s[f];
    }

    // ---- one pass = 16 ts x 4 lanes; lane j: quads {4j+1..4} +0/16/32/48 ----
    auto do_pass = [&](int p, float4 q0, float4 q1, float4 q2, float4 q3) {
        int gp = (p << 4) + g0;
        float f0s   = __shfl(f0s_l, gp, 64);
        float rev_g = __shfl(rev_l, gp, 64);
        float fq[NFMT], c1[NFMT], c2[NFMT];
        #pragma unroll
        for (int f = 0; f < NFMT; ++f) {
            fq[f] = __shfl(fqs[f], gp, 64);
            c1[f] = __shfl(c1s[f], gp, 64);
            c2[f] = __shfl(c2s[f], gp, 64);
        }
        float hb = (float)(j << 2);
        auto sd = [&](float k) {
            return __builtin_amdgcn_sinf(
                __builtin_amdgcn_fractf((hb + k) * rev_g));
        };
        v2f s01 = {sd(1.0f),  sd(2.0f)};
        v2f s23 = {sd(3.0f),  sd(4.0f)};
        v2f s45 = {sd(17.0f), sd(18.0f)};
        v2f s67 = {sd(19.0f), sd(20.0f)};
        float c16 = __builtin_amdgcn_cosf(
            __builtin_amdgcn_fractf(16.0f * rev_g));    // cos(16*theta)
        v2f cv = {2.0f * c16, 2.0f * c16};
        v2f s89 = cv * s45 - s01;                       // (hb+33,34)
        v2f sAB = cv * s67 - s23;                       // (hb+35,36)
        v2f sCD = cv * s89 - s45;                       // (hb+49,50)
        v2f sEF = cv * sAB - s67;                       // (hb+51,52)
        v2f acc2 = {0.0f, 0.0f};
        auto pairf = [&](float h1, v2f sn, float a0, float a1) {
            v2f hfl = {h1, h1 + 1.0f};
            v2f hs = f0s * hfl;                         // f0*h * 2^-10
            v2f pN = {1.0f, 1.0f}, pD = {1.0f, 1.0f};
            #pragma unroll
            for (int f = 0; f < NFMT; ++f) {
                v2f d = hs - fq[f];
                v2f e = d * d + c2[f];
                pN *= e + c1[f];
                pD *= e;
            }
            float R = __builtin_amdgcn_rcpf(pD.x * pD.y);
            v2f fac = {pN.x * pD.y * R, pN.y * pD.x * R};
            v2f fm;
            fm.x = (hs.x < NYQS) ? fac.x : 0.0f;        // nyquist mask
            fm.y = (hs.y < NYQS) ? fac.y : 0.0f;
            v2f aa = {a0, a1};
            acc2 += (sn * aa) * fm;
        };
        pairf(hb + 1.0f,  s01, q0.x, q0.y);
        pairf(hb + 3.0f,  s23, q0.z, q0.w);
        pairf(hb + 17.0f, s45, q1.x, q1.y);
        pairf(hb + 19.0f, s67, q1.z, q1.w);
        pairf(hb + 33.0f, s89, q2.x, q2.y);
        pairf(hb + 35.0f, sAB, q2.z, q2.w);
        pairf(hb + 49.0f, sCD, q3.x, q3.y);
        pairf(hb + 51.0f, sEF, q3.z, q3.w);
        float acc = acc2.x + acc2.y;
        acc += __shfl_xor(acc, 1, 64);
        acc += __shfl_xor(acc, 2, 64);
        if (j == 0) {
            if (!(f0s > 0.0f)) acc = 0.0f;              // voiced mask
            out[b * NT + t0 + (p << 4) + g0] = acc;
        }
    };

    // ---- 4 passes, double-buffered prefetch ----
    do_pass(0, A0, A1, A2, A3);
    AMPLD(A0, A1, A2, A3, 2)
    do_pass(1, B0, B1, B2, B3);
    AMPLD(B0, B1, B2, B3, 3)
    do_pass(2, A0, A1, A2, A3);
    do_pass(3, B0, B1, B2, B3);
    #undef AMPLD
}

extern "C" void kernel_launch(void* const* d_in, const int* in_sizes, int n_in,
                              void* d_out, int out_size, void* d_ws, size_t ws_size,
                              hipStream_t stream) {
    const float* f0    = (const float*)d_in[0];
    const float* amps  = (const float*)d_in[1];
    const float* ffq   = (const float*)d_in[2];
    const float* fbw   = (const float*)d_in[3];
    const float* fam   = (const float*)d_in[4];
    const float* initp = (const float*)d_in[5];
    float* out = (float*)d_out;

    double* part = (double*)d_ws;                    // NB*NCH doubles (48 KB)

    dim3 gchunk((NCH + 3) / 4, NB);
    k_partial<<<gchunk, 256, 0, stream>>>(f0, part);
    k_main<<<gchunk, 256, 0, stream>>>(f0, amps, ffq, fbw, fam, initp, part, out);
}